// Round 1
// baseline (33073.215 us; speedup 1.0000x reference)
//
#include <hip/hip_runtime.h>
#include <hip/hip_bf16.h>
#include <math.h>

#define B 32
#define T 64
#define S 256
#define H 512
#define E 256
#define V 32000
#define NH 8
#define HD 64
#define TS 63          // steps (T-1)
#define NR 2016        // TS*B rows
#define G3 1536        // 3*H

typedef short bf16x8 __attribute__((ext_vector_type(8)));
typedef float f32x4 __attribute__((ext_vector_type(4)));

__device__ __forceinline__ unsigned short f2bf(float f) {
    union { float f; unsigned u; } v; v.f = f;
    unsigned r = v.u + 0x7FFF + ((v.u >> 16) & 1);   // RNE
    return (unsigned short)(r >> 16);
}
__device__ __forceinline__ float clipf(float v, float lo, float hi) {
    return fminf(hi, fmaxf(lo, v));
}
__device__ __forceinline__ float sigf(float x) { return 1.0f / (1.0f + __expf(-x)); }

// ---------------- prolog kernels ----------------

__global__ void k_zero_t0(float* out) {
    int idx = blockIdx.x * 256 + threadIdx.x;        // over B*V/4
    int n = B * V / 4;
    if (idx < n) {
        int b = idx / (V / 4);
        int v4 = idx % (V / 4);
        float4* p = (float4*)(out + (size_t)b * T * V) + v4;
        *p = make_float4(0.f, 0.f, 0.f, 0.f);
    }
}

__global__ void k_init_h(const float* dec, float* h0, float* h1) {
    int i = blockIdx.x * 256 + threadIdx.x;
    if (i < B * H) {
        float v = clipf(dec[i], -10.f, 10.f);
        h0[i] = v; h1[i] = v;
    }
}

// Kh (clipped, transposed to [b][i][s]) and Vh ([b][s][i])
__global__ __launch_bounds__(256) void k_kv(const float* __restrict__ enc,
        const float* __restrict__ wk, const float* __restrict__ bk,
        const float* __restrict__ wv, const float* __restrict__ bv,
        float* __restrict__ kht, float* __restrict__ vh) {
    __shared__ float x[H];
    int row = blockIdx.x; int b = row / S; int s = row % S;
    const float* er = enc + (size_t)row * H;
    for (int i = threadIdx.x; i < H; i += 256) x[i] = er[i];
    __syncthreads();
    for (int i = threadIdx.x; i < H; i += 256) {
        const float* wr  = wk + (size_t)i * H;
        const float* wr2 = wv + (size_t)i * H;
        float aK = bk[i], aV = bv[i];
        for (int k = 0; k < H; k += 4) {
            float4 xv = *(const float4*)(x + k);
            float4 a  = *(const float4*)(wr + k);
            float4 c  = *(const float4*)(wr2 + k);
            aK += xv.x*a.x + xv.y*a.y + xv.z*a.z + xv.w*a.w;
            aV += xv.x*c.x + xv.y*c.y + xv.z*c.z + xv.w*c.w;
        }
        kht[((size_t)b * H + i) * S + s] = clipf(aK, -100.f, 100.f);
        vh[((size_t)b * S + s) * H + i] = aV;
    }
}

// GIE0[r][j] = b_ih0[j] + emb(r) . w_ih0[j, 0:512]   (emb includes b_ep)
__global__ __launch_bounds__(256) void k_gie(const int* __restrict__ tgt,
        const float* __restrict__ embt, const float* __restrict__ wep,
        const float* __restrict__ bep, const float* __restrict__ wih0,
        const float* __restrict__ bih0, float* __restrict__ gie) {
    __shared__ float er[E];
    __shared__ float xf[H];
    int r = blockIdx.x; int t = r >> 5; int b = r & 31;
    int tok = tgt[b * T + t];
    const float* em = embt + (size_t)tok * E;
    for (int i = threadIdx.x; i < E; i += 256) er[i] = em[i];
    __syncthreads();
    for (int i = threadIdx.x; i < H; i += 256) {
        const float* wr = wep + (size_t)i * E;
        float acc = bep[i];
        for (int k = 0; k < E; k += 4) {
            float4 xv = *(const float4*)(er + k);
            float4 a  = *(const float4*)(wr + k);
            acc += xv.x*a.x + xv.y*a.y + xv.z*a.z + xv.w*a.w;
        }
        xf[i] = acc;
    }
    __syncthreads();
    float* gr = gie + (size_t)r * G3;
    for (int j = threadIdx.x; j < G3; j += 256) {
        const float* wr = wih0 + (size_t)j * (2 * H);   // emb part = cols 0..511
        float acc = bih0[j];
        for (int k = 0; k < H; k += 4) {
            float4 xv = *(const float4*)(xf + k);
            float4 a  = *(const float4*)(wr + k);
            acc += xv.x*a.x + xv.y*a.y + xv.z*a.z + xv.w*a.w;
        }
        gr[j] = acc;
    }
}

__global__ void k_cvt(const float* __restrict__ wo1, const float* __restrict__ wo2,
                      unsigned short* __restrict__ w1b, unsigned short* __restrict__ w2b) {
    size_t idx = (size_t)blockIdx.x * 256 + threadIdx.x;
    size_t stride = (size_t)gridDim.x * 256;
    size_t n1 = (size_t)H * 2 * H;
    size_t n2 = (size_t)V * H;
    for (size_t i = idx; i < n1; i += stride) w1b[i] = f2bf(wo1[i]);
    for (size_t i = idx; i < n2; i += stride) w2b[i] = f2bf(wo2[i]);
}

// ---------------- sequential recurrence: 1 WG per batch element ----------------

__global__ __launch_bounds__(256) void k_seq(
        const float* __restrict__ kht, const float* __restrict__ vh,
        const float* __restrict__ gie, const int* __restrict__ mask,
        const float* __restrict__ wq,  const float* __restrict__ bq,
        const float* __restrict__ wo,  const float* __restrict__ bo,
        const float* __restrict__ wih0, const float* __restrict__ whh0, const float* __restrict__ bhh0,
        const float* __restrict__ wih1, const float* __restrict__ bih1,
        const float* __restrict__ whh1, const float* __restrict__ bhh1,
        const float* __restrict__ h0g, const float* __restrict__ h1g,
        unsigned short* __restrict__ comb) {
    __shared__ float h0L[H], h1L[H], h0n[H], qv[H], ctx[H], ctxo[H];
    __shared__ float sc[NH][S];
    __shared__ float cpart[4][H];
    int b = blockIdx.x, tid = threadIdx.x;
    for (int i = tid; i < H; i += 256) { h0L[i] = h0g[b * H + i]; h1L[i] = h1g[b * H + i]; }
    const float* khb = kht + (size_t)b * H * S;
    const float* vhb = vh  + (size_t)b * S * H;
    bool pad = (mask[b * S + tid] == 0);
    __syncthreads();

    for (int t = 0; t < TS; ++t) {
        int r = t * B + b;
        // q = clip(h1 @ wq.T + bq)
        for (int i = tid; i < H; i += 256) {
            const float* wr = wq + (size_t)i * H;
            float acc = bq[i];
            for (int k = 0; k < H; k += 4) {
                float4 xv = *(const float4*)(h1L + k);
                float4 a  = *(const float4*)(wr + k);
                acc += xv.x*a.x + xv.y*a.y + xv.z*a.z + xv.w*a.w;
            }
            qv[i] = clipf(acc, -100.f, 100.f);
        }
        __syncthreads();
        // scores: thread = s
        {
            int s = tid;
            for (int h = 0; h < NH; ++h) {
                const float* kr = khb + (size_t)(h * HD) * S + s;
                float acc = 0.f;
                #pragma unroll 8
                for (int d = 0; d < HD; ++d) acc += qv[h * HD + d] * kr[(size_t)d * S];
                sc[h][s] = pad ? -10000.0f : acc * 0.125f;
            }
        }
        __syncthreads();
        // softmax per head: wave w -> heads 2w, 2w+1
        {
            int wv_ = tid >> 6, lane = tid & 63;
            for (int hh = 0; hh < 2; ++hh) {
                int h = wv_ * 2 + hh;
                float v0 = sc[h][lane], v1 = sc[h][lane + 64];
                float v2 = sc[h][lane + 128], v3 = sc[h][lane + 192];
                float m = fmaxf(fmaxf(v0, v1), fmaxf(v2, v3));
                for (int off = 32; off >= 1; off >>= 1) m = fmaxf(m, __shfl_xor(m, off, 64));
                float e0 = __expf(v0 - m), e1 = __expf(v1 - m);
                float e2 = __expf(v2 - m), e3 = __expf(v3 - m);
                float sum = e0 + e1 + e2 + e3;
                for (int off = 32; off >= 1; off >>= 1) sum += __shfl_xor(sum, off, 64);
                float inv = 1.0f / sum;
                sc[h][lane] = e0 * inv; sc[h][lane + 64] = e1 * inv;
                sc[h][lane + 128] = e2 * inv; sc[h][lane + 192] = e3 * inv;
            }
        }
        __syncthreads();
        // ctx: s-chunk partials, coalesced over feature i
        {
            int c = tid >> 6, lane = tid & 63;
            float acc[8] = {0,0,0,0,0,0,0,0};
            for (int s = c * 64; s < c * 64 + 64; ++s) {
                const float* vr = vhb + (size_t)s * H;
                #pragma unroll
                for (int k = 0; k < 8; ++k) acc[k] += sc[k][s] * vr[lane + k * 64];
            }
            #pragma unroll
            for (int k = 0; k < 8; ++k) cpart[c][lane + k * 64] = acc[k];
        }
        __syncthreads();
        for (int i = tid; i < H; i += 256)
            ctx[i] = cpart[0][i] + cpart[1][i] + cpart[2][i] + cpart[3][i];
        __syncthreads();
        // ctxo = clip(ctx @ wo.T + bo)
        for (int i = tid; i < H; i += 256) {
            const float* wr = wo + (size_t)i * H;
            float acc = bo[i];
            for (int k = 0; k < H; k += 4) {
                float4 xv = *(const float4*)(ctx + k);
                float4 a  = *(const float4*)(wr + k);
                acc += xv.x*a.x + xv.y*a.y + xv.z*a.z + xv.w*a.w;
            }
            ctxo[i] = clipf(acc, -100.f, 100.f);
        }
        __syncthreads();
        // GRU0: features tid, tid+256
        const float* gr = gie + (size_t)r * G3;
        float h0new[2];
        #pragma unroll
        for (int u = 0; u < 2; ++u) {
            int j = tid + u * 256;
            float gir = gr[j], giz = gr[j + H], gin = gr[j + 2 * H];
            float ghr = bhh0[j], ghz = bhh0[j + H], ghn = bhh0[j + 2 * H];
            const float* wir = wih0 + (size_t)j * (2 * H) + H;
            const float* wiz = wih0 + (size_t)(j + H) * (2 * H) + H;
            const float* win = wih0 + (size_t)(j + 2 * H) * (2 * H) + H;
            const float* whr = whh0 + (size_t)j * H;
            const float* whz = whh0 + (size_t)(j + H) * H;
            const float* whn = whh0 + (size_t)(j + 2 * H) * H;
            for (int k = 0; k < H; k += 4) {
                float4 xv = *(const float4*)(ctxo + k);
                float4 hv = *(const float4*)(h0L + k);
                float4 a0 = *(const float4*)(wir + k);
                float4 a1 = *(const float4*)(wiz + k);
                float4 a2 = *(const float4*)(win + k);
                float4 b0 = *(const float4*)(whr + k);
                float4 b1 = *(const float4*)(whz + k);
                float4 b2 = *(const float4*)(whn + k);
                gir += xv.x*a0.x + xv.y*a0.y + xv.z*a0.z + xv.w*a0.w;
                giz += xv.x*a1.x + xv.y*a1.y + xv.z*a1.z + xv.w*a1.w;
                gin += xv.x*a2.x + xv.y*a2.y + xv.z*a2.z + xv.w*a2.w;
                ghr += hv.x*b0.x + hv.y*b0.y + hv.z*b0.z + hv.w*b0.w;
                ghz += hv.x*b1.x + hv.y*b1.y + hv.z*b1.z + hv.w*b1.w;
                ghn += hv.x*b2.x + hv.y*b2.y + hv.z*b2.z + hv.w*b2.w;
            }
            float rr = sigf(gir + ghr);
            float zz = sigf(giz + ghz);
            float nn = tanhf(gin + rr * ghn);
            h0new[u] = (1.f - zz) * nn + zz * h0L[j];
        }
        h0n[tid] = h0new[0]; h0n[tid + 256] = h0new[1];
        __syncthreads();
        // GRU1 (input = unclipped h0n)
        float h1new[2];
        #pragma unroll
        for (int u = 0; u < 2; ++u) {
            int j = tid + u * 256;
            float gir = bih1[j], giz = bih1[j + H], gin = bih1[j + 2 * H];
            float ghr = bhh1[j], ghz = bhh1[j + H], ghn = bhh1[j + 2 * H];
            const float* wir = wih1 + (size_t)j * H;
            const float* wiz = wih1 + (size_t)(j + H) * H;
            const float* win = wih1 + (size_t)(j + 2 * H) * H;
            const float* whr = whh1 + (size_t)j * H;
            const float* whz = whh1 + (size_t)(j + H) * H;
            const float* whn = whh1 + (size_t)(j + 2 * H) * H;
            for (int k = 0; k < H; k += 4) {
                float4 xv = *(const float4*)(h0n + k);
                float4 hv = *(const float4*)(h1L + k);
                float4 a0 = *(const float4*)(wir + k);
                float4 a1 = *(const float4*)(wiz + k);
                float4 a2 = *(const float4*)(win + k);
                float4 b0 = *(const float4*)(whr + k);
                float4 b1 = *(const float4*)(whz + k);
                float4 b2 = *(const float4*)(whn + k);
                gir += xv.x*a0.x + xv.y*a0.y + xv.z*a0.z + xv.w*a0.w;
                giz += xv.x*a1.x + xv.y*a1.y + xv.z*a1.z + xv.w*a1.w;
                gin += xv.x*a2.x + xv.y*a2.y + xv.z*a2.z + xv.w*a2.w;
                ghr += hv.x*b0.x + hv.y*b0.y + hv.z*b0.z + hv.w*b0.w;
                ghz += hv.x*b1.x + hv.y*b1.y + hv.z*b1.z + hv.w*b1.w;
                ghn += hv.x*b2.x + hv.y*b2.y + hv.z*b2.z + hv.w*b2.w;
            }
            float rr = sigf(gir + ghr);
            float zz = sigf(giz + ghz);
            float nn = tanhf(gin + rr * ghn);
            h1new[u] = (1.f - zz) * nn + zz * h1L[j];
        }
        // comb row: [h1 (unclipped), ctxo]
        {
            unsigned short* cr = comb + (size_t)r * 1024;
            cr[tid] = f2bf(h1new[0]); cr[tid + 256] = f2bf(h1new[1]);
            cr[H + tid] = f2bf(ctxo[tid]); cr[H + tid + 256] = f2bf(ctxo[tid + 256]);
        }
        __syncthreads();   // all reads of h0L/h1L done
        h0L[tid] = clipf(h0n[tid], -10.f, 10.f);
        h0L[tid + 256] = clipf(h0n[tid + 256], -10.f, 10.f);
        h1L[tid] = clipf(h1new[0], -10.f, 10.f);
        h1L[tid + 256] = clipf(h1new[1], -10.f, 10.f);
        __syncthreads();
    }
}

// ---------------- MFMA bf16 GEMMs for output MLP ----------------
// A [M,K] row-major bf16, Bm points at n-base of weight [N,K] row-major bf16.
__device__ __forceinline__ void mfma_tile64(const unsigned short* A, int lda,
        const unsigned short* Bm, int ldb, int K, int arow0, int Mmax, f32x4 acc[4][4]) {
    int lane = threadIdx.x & 63;
    int m16 = lane & 15, q = lane >> 4;
    const unsigned short* ar[4];
    const unsigned short* br[4];
    #pragma unroll
    for (int mi = 0; mi < 4; ++mi) {
        int row = arow0 + mi * 16 + m16; if (row >= Mmax) row = Mmax - 1;
        ar[mi] = A + (size_t)row * lda + q * 8;
    }
    #pragma unroll
    for (int ni = 0; ni < 4; ++ni) br[ni] = Bm + (size_t)(ni * 16 + m16) * ldb + q * 8;
    for (int k = 0; k < K; k += 32) {
        bf16x8 af[4], bfr[4];
        #pragma unroll
        for (int mi = 0; mi < 4; ++mi) af[mi] = *(const bf16x8*)(ar[mi] + k);
        #pragma unroll
        for (int ni = 0; ni < 4; ++ni) bfr[ni] = *(const bf16x8*)(br[ni] + k);
        #pragma unroll
        for (int mi = 0; mi < 4; ++mi)
            #pragma unroll
            for (int ni = 0; ni < 4; ++ni)
                acc[mi][ni] = __builtin_amdgcn_mfma_f32_16x16x32_bf16(af[mi], bfr[ni], acc[mi][ni], 0, 0, 0);
    }
}

// H1 = bf16(relu(comb @ w_o1.T + b_o1))   [2016, 512]
__global__ __launch_bounds__(256) void k_g1(const unsigned short* __restrict__ comb,
        const unsigned short* __restrict__ w1b, const float* __restrict__ b1,
        unsigned short* __restrict__ h1out) {
    int wave = threadIdx.x >> 6, lane = threadIdx.x & 63;
    int wm = wave >> 1, wn = wave & 1;
    int m0 = blockIdx.y * 128 + wm * 64;
    int n0 = blockIdx.x * 128 + wn * 64;
    f32x4 acc[4][4];
    #pragma unroll
    for (int i = 0; i < 4; ++i)
        #pragma unroll
        for (int j = 0; j < 4; ++j) acc[i][j] = (f32x4){0.f, 0.f, 0.f, 0.f};
    mfma_tile64(comb, 1024, w1b + (size_t)n0 * 1024, 1024, 1024, m0, NR, acc);
    int q = lane >> 4, m16 = lane & 15;
    #pragma unroll
    for (int mi = 0; mi < 4; ++mi)
        #pragma unroll
        for (int ni = 0; ni < 4; ++ni) {
            int n = n0 + ni * 16 + m16;
            float bias = b1[n];
            #pragma unroll
            for (int rg = 0; rg < 4; ++rg) {
                int row = m0 + mi * 16 + q * 4 + rg;
                if (row < NR) {
                    float v = fmaxf(acc[mi][ni][rg] + bias, 0.f);
                    h1out[(size_t)row * 512 + n] = f2bf(v);
                }
            }
        }
}

// out[b, t+1, :] = clip(H1 @ w_o2.T + b_o2, +-100)
__global__ __launch_bounds__(256) void k_g2(const unsigned short* __restrict__ h1b,
        const unsigned short* __restrict__ w2b, const float* __restrict__ b2,
        float* __restrict__ out) {
    int wave = threadIdx.x >> 6, lane = threadIdx.x & 63;
    int wm = wave >> 1, wn = wave & 1;
    int m0 = blockIdx.y * 128 + wm * 64;
    int n0 = blockIdx.x * 128 + wn * 64;
    f32x4 acc[4][4];
    #pragma unroll
    for (int i = 0; i < 4; ++i)
        #pragma unroll
        for (int j = 0; j < 4; ++j) acc[i][j] = (f32x4){0.f, 0.f, 0.f, 0.f};
    mfma_tile64(h1b, 512, w2b + (size_t)n0 * 512, 512, 512, m0, NR, acc);
    int q = lane >> 4, m16 = lane & 15;
    #pragma unroll
    for (int mi = 0; mi < 4; ++mi)
        #pragma unroll
        for (int ni = 0; ni < 4; ++ni) {
            int n = n0 + ni * 16 + m16;
            float bias = b2[n];
            #pragma unroll
            for (int rg = 0; rg < 4; ++rg) {
                int row = m0 + mi * 16 + q * 4 + rg;
                if (row < NR) {
                    int t = row >> 5, b = row & 31;
                    float v = clipf(acc[mi][ni][rg] + bias, -100.f, 100.f);
                    out[(size_t)b * T * V + (size_t)(t + 1) * V + n] = v;
                }
            }
        }
}

// ---------------- launch ----------------

extern "C" void kernel_launch(void* const* d_in, const int* in_sizes, int n_in,
                              void* d_out, int out_size, void* d_ws, size_t ws_size,
                              hipStream_t stream) {
    const int*   tgt  = (const int*)d_in[0];
    const float* enc  = (const float*)d_in[1];
    const float* dec  = (const float*)d_in[2];
    const int*   mask = (const int*)d_in[3];
    const float* embt = (const float*)d_in[4];
    const float* wep  = (const float*)d_in[5];  const float* bep = (const float*)d_in[6];
    const float* wq   = (const float*)d_in[7];  const float* bq  = (const float*)d_in[8];
    const float* wk   = (const float*)d_in[9];  const float* bk  = (const float*)d_in[10];
    const float* wv   = (const float*)d_in[11]; const float* bv  = (const float*)d_in[12];
    const float* wo   = (const float*)d_in[13]; const float* bo  = (const float*)d_in[14];
    const float* wih0 = (const float*)d_in[15]; const float* whh0 = (const float*)d_in[16];
    const float* bih0 = (const float*)d_in[17]; const float* bhh0 = (const float*)d_in[18];
    const float* wih1 = (const float*)d_in[19]; const float* whh1 = (const float*)d_in[20];
    const float* bih1 = (const float*)d_in[21]; const float* bhh1 = (const float*)d_in[22];
    const float* wo1  = (const float*)d_in[23]; const float* bo1 = (const float*)d_in[24];
    const float* wo2  = (const float*)d_in[25]; const float* bo2 = (const float*)d_in[26];
    float* out = (float*)d_out;
    char* ws = (char*)d_ws;

    float* kht          = (float*)(ws + 0);                    // 16,777,216 B
    float* vh           = (float*)(ws + 16777216);             // 16,777,216 B
    float* gie          = (float*)(ws + 33554432);             // 12,386,304 B
    unsigned short* comb = (unsigned short*)(ws + 45940736);   //  4,128,768 B
    unsigned short* h1b  = (unsigned short*)(ws + 50069504);   //  2,064,384 B
    unsigned short* w1b  = (unsigned short*)(ws + 52133888);   //  1,048,576 B
    unsigned short* w2b  = (unsigned short*)(ws + 53182464);   // 32,768,000 B
    float* h0s          = (float*)(ws + 85950464);             //     65,536 B
    float* h1s          = (float*)(ws + 86016000);             //     65,536 B

    hipLaunchKernelGGL(k_zero_t0, dim3(1000), dim3(256), 0, stream, out);
    hipLaunchKernelGGL(k_init_h, dim3(64), dim3(256), 0, stream, dec, h0s, h1s);
    hipLaunchKernelGGL(k_kv, dim3(B * S), dim3(256), 0, stream, enc, wk, bk, wv, bv, kht, vh);
    hipLaunchKernelGGL(k_gie, dim3(NR), dim3(256), 0, stream, tgt, embt, wep, bep, wih0, bih0, gie);
    hipLaunchKernelGGL(k_cvt, dim3(4096), dim3(256), 0, stream, wo1, wo2, w1b, w2b);
    hipLaunchKernelGGL(k_seq, dim3(B), dim3(256), 0, stream, kht, vh, gie, mask, wq, bq, wo, bo,
                       wih0, whh0, bhh0, wih1, bih1, whh1, bhh1, h0s, h1s, comb);
    hipLaunchKernelGGL(k_g1, dim3(4, 16), dim3(256), 0, stream, comb, w1b, bo1, h1b);
    hipLaunchKernelGGL(k_g2, dim3(250, 16), dim3(256), 0, stream, h1b, w2b, bo2, out);
}

// Round 2
// 10813.998 us; speedup vs baseline: 3.0584x; 3.0584x over previous
//
#include <hip/hip_runtime.h>
#include <hip/hip_bf16.h>
#include <math.h>

#define B 32
#define T 64
#define S 256
#define H 512
#define E 256
#define V 32000
#define NH 8
#define HD 64
#define TS 63          // steps (T-1)
#define NR 2016        // TS*B rows
#define G3 1536        // 3*H
#define GRID_REC 256

typedef short bf16x8 __attribute__((ext_vector_type(8)));
typedef float f32x4 __attribute__((ext_vector_type(4)));

__device__ __forceinline__ unsigned short f2bf(float f) {
    union { float f; unsigned u; } v; v.f = f;
    unsigned r = v.u + 0x7FFF + ((v.u >> 16) & 1);   // RNE
    return (unsigned short)(r >> 16);
}
__device__ __forceinline__ float clipf(float v, float lo, float hi) {
    return fminf(hi, fmaxf(lo, v));
}
__device__ __forceinline__ float sigf(float x) { return 1.0f / (1.0f + __expf(-x)); }

// ---------------- prolog kernels ----------------

__global__ void k_zero_t0(float* out) {
    int idx = blockIdx.x * 256 + threadIdx.x;        // over B*V/4
    int n = B * V / 4;
    if (idx < n) {
        int b = idx / (V / 4);
        int v4 = idx % (V / 4);
        float4* p = (float4*)(out + (size_t)b * T * V) + v4;
        *p = make_float4(0.f, 0.f, 0.f, 0.f);
    }
}

// h0c/h1c in [j][b] layout (j*32+b); h1r row-major [b][j]
__global__ void k_init_h(const float* dec, float* h0c, float* h1c, float* h1r) {
    int i = blockIdx.x * 256 + threadIdx.x;
    if (i < B * H) {
        int b = i >> 9, j = i & 511;
        float v = clipf(dec[i], -10.f, 10.f);
        h0c[j * 32 + b] = v; h1c[j * 32 + b] = v; h1r[i] = v;
    }
}

// Kh (clipped, transposed to [b][i][s]) and Vh ([b][s][i])
__global__ __launch_bounds__(256) void k_kv(const float* __restrict__ enc,
        const float* __restrict__ wk, const float* __restrict__ bk,
        const float* __restrict__ wv, const float* __restrict__ bv,
        float* __restrict__ kht, float* __restrict__ vh) {
    __shared__ float x[H];
    int row = blockIdx.x; int b = row / S; int s = row % S;
    const float* er = enc + (size_t)row * H;
    for (int i = threadIdx.x; i < H; i += 256) x[i] = er[i];
    __syncthreads();
    for (int i = threadIdx.x; i < H; i += 256) {
        const float* wr  = wk + (size_t)i * H;
        const float* wr2 = wv + (size_t)i * H;
        float aK = bk[i], aV = bv[i];
        for (int k = 0; k < H; k += 4) {
            float4 xv = *(const float4*)(x + k);
            float4 a  = *(const float4*)(wr + k);
            float4 c  = *(const float4*)(wr2 + k);
            aK += xv.x*a.x + xv.y*a.y + xv.z*a.z + xv.w*a.w;
            aV += xv.x*c.x + xv.y*c.y + xv.z*c.z + xv.w*c.w;
        }
        kht[((size_t)b * H + i) * S + s] = clipf(aK, -100.f, 100.f);
        vh[((size_t)b * S + s) * H + i] = aV;
    }
}

// GIE0[(t*1536+j)*32+b] = b_ih0[j] + emb(t,b) . w_ih0[j, 0:512]
__global__ __launch_bounds__(256) void k_gie(const int* __restrict__ tgt,
        const float* __restrict__ embt, const float* __restrict__ wep,
        const float* __restrict__ bep, const float* __restrict__ wih0,
        const float* __restrict__ bih0, float* __restrict__ gie) {
    __shared__ float er[E];
    __shared__ float xf[H];
    int r = blockIdx.x; int t = r >> 5; int b = r & 31;
    int tok = tgt[b * T + t];
    const float* em = embt + (size_t)tok * E;
    for (int i = threadIdx.x; i < E; i += 256) er[i] = em[i];
    __syncthreads();
    for (int i = threadIdx.x; i < H; i += 256) {
        const float* wr = wep + (size_t)i * E;
        float acc = bep[i];
        for (int k = 0; k < E; k += 4) {
            float4 xv = *(const float4*)(er + k);
            float4 a  = *(const float4*)(wr + k);
            acc += xv.x*a.x + xv.y*a.y + xv.z*a.z + xv.w*a.w;
        }
        xf[i] = acc;
    }
    __syncthreads();
    for (int j = threadIdx.x; j < G3; j += 256) {
        const float* wr = wih0 + (size_t)j * (2 * H);   // emb part = cols 0..511
        float acc = bih0[j];
        for (int k = 0; k < H; k += 4) {
            float4 xv = *(const float4*)(xf + k);
            float4 a  = *(const float4*)(wr + k);
            acc += xv.x*a.x + xv.y*a.y + xv.z*a.z + xv.w*a.w;
        }
        gie[((size_t)t * G3 + j) * 32 + b] = acc;
    }
}

__global__ void k_cvt(const float* __restrict__ wo1, const float* __restrict__ wo2,
                      unsigned short* __restrict__ w1b, unsigned short* __restrict__ w2b) {
    size_t idx = (size_t)blockIdx.x * 256 + threadIdx.x;
    size_t stride = (size_t)gridDim.x * 256;
    size_t n1 = (size_t)H * 2 * H;
    size_t n2 = (size_t)V * H;
    for (size_t i = idx; i < n1; i += stride) w1b[i] = f2bf(wo1[i]);
    for (size_t i = idx; i < n2; i += stride) w2b[i] = f2bf(wo2[i]);
}

// ---------------- persistent recurrence kernel ----------------

__device__ __forceinline__ void gbar(unsigned* bar, int ep) {
    __syncthreads();
    if (threadIdx.x == 0) {
        __builtin_amdgcn_fence(__ATOMIC_RELEASE, "agent");
        unsigned* c = bar + ep * 32;
        __hip_atomic_fetch_add(c, 1u, __ATOMIC_RELAXED, __HIP_MEMORY_SCOPE_AGENT);
        while (__hip_atomic_load(c, __ATOMIC_RELAXED, __HIP_MEMORY_SCOPE_AGENT) < (unsigned)GRID_REC) {
            __builtin_amdgcn_s_sleep(1);
        }
        __builtin_amdgcn_fence(__ATOMIC_ACQUIRE, "agent");
    }
    __syncthreads();
}

// src layout [512][32] -> X[b*513 + k]
__device__ __forceinline__ void stageX(float* X, const float* __restrict__ src) {
    for (int i = threadIdx.x; i < 4096; i += 256) {
        float4 v = ((const float4*)src)[i];
        int j = (4 * i) >> 5;
        int b0 = (4 * i) & 31;
        X[(b0 + 0) * 513 + j] = v.x;
        X[(b0 + 1) * 513 + j] = v.y;
        X[(b0 + 2) * 513 + j] = v.z;
        X[(b0 + 3) * 513 + j] = v.w;
    }
}

__device__ __forceinline__ float dot128(const float* __restrict__ w, const float* x) {
    float acc = 0.f;
    #pragma unroll 8
    for (int k = 0; k < 128; k += 4) {
        float4 a = *(const float4*)(w + k);
        acc += a.x * x[k] + a.y * x[k+1] + a.z * x[k+2] + a.w * x[k+3];
    }
    return acc;
}

__device__ __forceinline__ void dot128x3(const float* __restrict__ w0,
        const float* __restrict__ w1, const float* __restrict__ w2,
        const float* x, float* out3) {
    float a0 = 0.f, a1 = 0.f, a2 = 0.f;
    #pragma unroll 8
    for (int k = 0; k < 128; k += 4) {
        float x0 = x[k], x1 = x[k+1], x2 = x[k+2], x3 = x[k+3];
        float4 wa = *(const float4*)(w0 + k);
        float4 wb = *(const float4*)(w1 + k);
        float4 wc = *(const float4*)(w2 + k);
        a0 += wa.x*x0 + wa.y*x1 + wa.z*x2 + wa.w*x3;
        a1 += wb.x*x0 + wb.y*x1 + wb.z*x2 + wb.w*x3;
        a2 += wc.x*x0 + wc.y*x1 + wc.z*x2 + wc.w*x3;
    }
    out3[0] = a0; out3[1] = a1; out3[2] = a2;
}

__global__ __launch_bounds__(256) void k_rec(
        const float* __restrict__ kht, const float* __restrict__ vh,
        const float* __restrict__ gie, const int* __restrict__ maskp,
        const float* __restrict__ wq,  const float* __restrict__ bq,
        const float* __restrict__ wo,  const float* __restrict__ bo,
        const float* __restrict__ wih0, const float* __restrict__ whh0, const float* __restrict__ bhh0,
        const float* __restrict__ wih1, const float* __restrict__ bih1,
        const float* __restrict__ whh1, const float* __restrict__ bhh1,
        float* __restrict__ ctxA, float* __restrict__ ctxo,
        float* __restrict__ h0c, float* __restrict__ h0n,
        float* __restrict__ h1c, float* __restrict__ h1r,
        unsigned short* __restrict__ comb, unsigned* bar) {
    __shared__ float X[32 * 513];
    __shared__ float sc[S];
    __shared__ float qv[64];
    __shared__ float pq[64 * 4];
    __shared__ float cp[4 * 64];
    __shared__ float pr[4 * 32 * 6];
    __shared__ float red[8];

    const int wg = blockIdx.x, tid = threadIdx.x;
    const int ab = wg >> 3, ah = wg & 7;          // phase A identity (b, head)
    const int j0 = wg * 2;                        // B/C/D: rows j0, j0+1
    const int j2 = tid >> 7;
    const int pp = (tid >> 5) & 3;
    const int bb = tid & 31;
    const int jme = j0 + j2;
    const int wid = tid >> 6;
    const bool fin = tid < 64;
    const int fj2 = tid >> 5, fb = tid & 31;      // valid when fin
    const bool apad = (maskp[ab * S + tid] == 0);
    int ep = 0;

    for (int t = 0; t < TS; ++t) {
        // ====== Phase A: q + attention for (ab, ah) ======
        if (tid < 128) {
            float4 v = *(const float4*)(h1r + ab * H + tid * 4);
            X[tid*4+0] = v.x; X[tid*4+1] = v.y; X[tid*4+2] = v.z; X[tid*4+3] = v.w;
        }
        __syncthreads();
        {   // q partials: f = tid>>2, p = tid&3
            int f = tid >> 2, p = tid & 3;
            const float* wr = wq + (size_t)(ah * 64 + f) * H + p * 128;
            pq[f * 4 + p] = dot128(wr, X + p * 128);
        }
        __syncthreads();
        if (tid < 64)
            qv[tid] = clipf(pq[tid*4] + pq[tid*4+1] + pq[tid*4+2] + pq[tid*4+3]
                            + bq[ah * 64 + tid], -100.f, 100.f);
        __syncthreads();
        {   // scores: thread = s
            const float* kr = kht + ((size_t)ab * H + ah * 64) * S + tid;
            float acc = 0.f;
            #pragma unroll 8
            for (int d = 0; d < 64; ++d) acc += qv[d] * kr[(size_t)d * S];
            sc[tid] = apad ? -10000.f : acc * 0.125f;
        }
        __syncthreads();
        {   // softmax over 256
            float v = sc[tid];
            float m = v;
            for (int o = 32; o >= 1; o >>= 1) m = fmaxf(m, __shfl_xor(m, o, 64));
            if ((tid & 63) == 0) red[wid] = m;
            __syncthreads();
            m = fmaxf(fmaxf(red[0], red[1]), fmaxf(red[2], red[3]));
            float e = __expf(v - m);
            float s = e;
            for (int o = 32; o >= 1; o >>= 1) s += __shfl_xor(s, o, 64);
            if ((tid & 63) == 0) red[4 + wid] = s;
            __syncthreads();
            float inv = 1.f / (red[4] + red[5] + red[6] + red[7]);
            sc[tid] = e * inv;
        }
        __syncthreads();
        {   // ctx: d = tid&63, chunk c = tid>>6
            int d = tid & 63, c = tid >> 6;
            const float* vr = vh + ((size_t)ab * S + c * 64) * H + ah * 64 + d;
            float acc = 0.f;
            #pragma unroll 4
            for (int s2 = 0; s2 < 64; ++s2) acc += sc[c * 64 + s2] * vr[(size_t)s2 * H];
            cp[c * 64 + d] = acc;
        }
        __syncthreads();
        if (tid < 64)
            ctxA[(ah * 64 + tid) * 32 + ab] = cp[tid] + cp[64 + tid] + cp[128 + tid] + cp[192 + tid];
        gbar(bar, ep++);

        // ====== Phase B: ctxo = clip(ctx @ wo.T + bo) ======
        stageX(X, ctxA);
        __syncthreads();
        {
            const float* wr = wo + (size_t)jme * H + pp * 128;
            float acc = dot128(wr, X + bb * 513 + pp * 128);
            acc += __shfl_xor(acc, 32, 64);
            if ((tid & 63) < 32) pr[wid * 32 + bb] = acc;
        }
        __syncthreads();
        if (fin) {
            int j = j0 + fj2;
            float v = pr[(fj2 * 2) * 32 + fb] + pr[(fj2 * 2 + 1) * 32 + fb] + bo[j];
            v = clipf(v, -100.f, 100.f);
            ctxo[j * 32 + fb] = v;
            comb[((size_t)(t * 32 + fb)) * 1024 + 512 + j] = f2bf(v);
        }
        gbar(bar, ep++);

        // ====== Phase C: GRU0 ======
        stageX(X, ctxo);
        __syncthreads();
        float gi3[3], gh3[3];
        dot128x3(wih0 + (size_t)jme * 1024 + 512 + pp * 128,
                 wih0 + (size_t)(jme + 512) * 1024 + 512 + pp * 128,
                 wih0 + (size_t)(jme + 1024) * 1024 + 512 + pp * 128,
                 X + bb * 513 + pp * 128, gi3);
        __syncthreads();
        stageX(X, h0c);
        __syncthreads();
        dot128x3(whh0 + (size_t)jme * H + pp * 128,
                 whh0 + (size_t)(jme + 512) * H + pp * 128,
                 whh0 + (size_t)(jme + 1024) * H + pp * 128,
                 X + bb * 513 + pp * 128, gh3);
        {
            #pragma unroll
            for (int g = 0; g < 3; ++g) {
                gi3[g] += __shfl_xor(gi3[g], 32, 64);
                gh3[g] += __shfl_xor(gh3[g], 32, 64);
            }
            if ((tid & 63) < 32) {
                float* p = pr + (wid * 32 + bb) * 6;
                p[0] = gi3[0]; p[1] = gi3[1]; p[2] = gi3[2];
                p[3] = gh3[0]; p[4] = gh3[1]; p[5] = gh3[2];
            }
        }
        __syncthreads();
        if (fin) {
            int j = j0 + fj2;
            const float* pa = pr + ((fj2 * 2) * 32 + fb) * 6;
            const float* pb = pr + ((fj2 * 2 + 1) * 32 + fb) * 6;
            float gir = pa[0] + pb[0] + gie[((size_t)t * G3 + j) * 32 + fb];
            float giz = pa[1] + pb[1] + gie[((size_t)t * G3 + 512 + j) * 32 + fb];
            float gin = pa[2] + pb[2] + gie[((size_t)t * G3 + 1024 + j) * 32 + fb];
            float ghr = pa[3] + pb[3] + bhh0[j];
            float ghz = pa[4] + pb[4] + bhh0[512 + j];
            float ghn = pa[5] + pb[5] + bhh0[1024 + j];
            float r_ = sigf(gir + ghr);
            float z_ = sigf(giz + ghz);
            float n_ = tanhf(gin + r_ * ghn);
            float h0old = X[fb * 513 + j];              // X holds h0c
            float hn = (1.f - z_) * n_ + z_ * h0old;
            h0n[j * 32 + fb] = hn;
            h0c[j * 32 + fb] = clipf(hn, -10.f, 10.f);
        }
        gbar(bar, ep++);

        // ====== Phase D: GRU1 ======
        stageX(X, h0n);
        __syncthreads();
        dot128x3(wih1 + (size_t)jme * H + pp * 128,
                 wih1 + (size_t)(jme + 512) * H + pp * 128,
                 wih1 + (size_t)(jme + 1024) * H + pp * 128,
                 X + bb * 513 + pp * 128, gi3);
        __syncthreads();
        stageX(X, h1c);
        __syncthreads();
        dot128x3(whh1 + (size_t)jme * H + pp * 128,
                 whh1 + (size_t)(jme + 512) * H + pp * 128,
                 whh1 + (size_t)(jme + 1024) * H + pp * 128,
                 X + bb * 513 + pp * 128, gh3);
        {
            #pragma unroll
            for (int g = 0; g < 3; ++g) {
                gi3[g] += __shfl_xor(gi3[g], 32, 64);
                gh3[g] += __shfl_xor(gh3[g], 32, 64);
            }
            if ((tid & 63) < 32) {
                float* p = pr + (wid * 32 + bb) * 6;
                p[0] = gi3[0]; p[1] = gi3[1]; p[2] = gi3[2];
                p[3] = gh3[0]; p[4] = gh3[1]; p[5] = gh3[2];
            }
        }
        __syncthreads();
        if (fin) {
            int j = j0 + fj2;
            const float* pa = pr + ((fj2 * 2) * 32 + fb) * 6;
            const float* pb = pr + ((fj2 * 2 + 1) * 32 + fb) * 6;
            float gir = pa[0] + pb[0] + bih1[j];
            float giz = pa[1] + pb[1] + bih1[512 + j];
            float gin = pa[2] + pb[2] + bih1[1024 + j];
            float ghr = pa[3] + pb[3] + bhh1[j];
            float ghz = pa[4] + pb[4] + bhh1[512 + j];
            float ghn = pa[5] + pb[5] + bhh1[1024 + j];
            float r_ = sigf(gir + ghr);
            float z_ = sigf(giz + ghz);
            float n_ = tanhf(gin + r_ * ghn);
            float h1old = X[fb * 513 + j];              // X holds h1c
            float hn = (1.f - z_) * n_ + z_ * h1old;
            float hc = clipf(hn, -10.f, 10.f);
            h1c[j * 32 + fb] = hc;
            h1r[fb * H + j] = hc;
            comb[((size_t)(t * 32 + fb)) * 1024 + j] = f2bf(hn);
        }
        gbar(bar, ep++);
    }
}

// ---------------- MFMA bf16 GEMMs for output MLP ----------------
__device__ __forceinline__ void mfma_tile64(const unsigned short* A, int lda,
        const unsigned short* Bm, int ldb, int K, int arow0, int Mmax, f32x4 acc[4][4]) {
    int lane = threadIdx.x & 63;
    int m16 = lane & 15, q = lane >> 4;
    const unsigned short* ar[4];
    const unsigned short* br[4];
    #pragma unroll
    for (int mi = 0; mi < 4; ++mi) {
        int row = arow0 + mi * 16 + m16; if (row >= Mmax) row = Mmax - 1;
        ar[mi] = A + (size_t)row * lda + q * 8;
    }
    #pragma unroll
    for (int ni = 0; ni < 4; ++ni) br[ni] = Bm + (size_t)(ni * 16 + m16) * ldb + q * 8;
    for (int k = 0; k < K; k += 32) {
        bf16x8 af[4], bfr[4];
        #pragma unroll
        for (int mi = 0; mi < 4; ++mi) af[mi] = *(const bf16x8*)(ar[mi] + k);
        #pragma unroll
        for (int ni = 0; ni < 4; ++ni) bfr[ni] = *(const bf16x8*)(br[ni] + k);
        #pragma unroll
        for (int mi = 0; mi < 4; ++mi)
            #pragma unroll
            for (int ni = 0; ni < 4; ++ni)
                acc[mi][ni] = __builtin_amdgcn_mfma_f32_16x16x32_bf16(af[mi], bfr[ni], acc[mi][ni], 0, 0, 0);
    }
}

__global__ __launch_bounds__(256) void k_g1(const unsigned short* __restrict__ comb,
        const unsigned short* __restrict__ w1b, const float* __restrict__ b1,
        unsigned short* __restrict__ h1out) {
    int wave = threadIdx.x >> 6, lane = threadIdx.x & 63;
    int wm = wave >> 1, wn = wave & 1;
    int m0 = blockIdx.y * 128 + wm * 64;
    int n0 = blockIdx.x * 128 + wn * 64;
    f32x4 acc[4][4];
    #pragma unroll
    for (int i = 0; i < 4; ++i)
        #pragma unroll
        for (int j = 0; j < 4; ++j) acc[i][j] = (f32x4){0.f, 0.f, 0.f, 0.f};
    mfma_tile64(comb, 1024, w1b + (size_t)n0 * 1024, 1024, 1024, m0, NR, acc);
    int q = lane >> 4, m16 = lane & 15;
    #pragma unroll
    for (int mi = 0; mi < 4; ++mi)
        #pragma unroll
        for (int ni = 0; ni < 4; ++ni) {
            int n = n0 + ni * 16 + m16;
            float bias = b1[n];
            #pragma unroll
            for (int rg = 0; rg < 4; ++rg) {
                int row = m0 + mi * 16 + q * 4 + rg;
                if (row < NR) {
                    float v = fmaxf(acc[mi][ni][rg] + bias, 0.f);
                    h1out[(size_t)row * 512 + n] = f2bf(v);
                }
            }
        }
}

__global__ __launch_bounds__(256) void k_g2(const unsigned short* __restrict__ h1b,
        const unsigned short* __restrict__ w2b, const float* __restrict__ b2,
        float* __restrict__ out) {
    int wave = threadIdx.x >> 6, lane = threadIdx.x & 63;
    int wm = wave >> 1, wn = wave & 1;
    int m0 = blockIdx.y * 128 + wm * 64;
    int n0 = blockIdx.x * 128 + wn * 64;
    f32x4 acc[4][4];
    #pragma unroll
    for (int i = 0; i < 4; ++i)
        #pragma unroll
        for (int j = 0; j < 4; ++j) acc[i][j] = (f32x4){0.f, 0.f, 0.f, 0.f};
    mfma_tile64(h1b, 512, w2b + (size_t)n0 * 512, 512, 512, m0, NR, acc);
    int q = lane >> 4, m16 = lane & 15;
    #pragma unroll
    for (int mi = 0; mi < 4; ++mi)
        #pragma unroll
        for (int ni = 0; ni < 4; ++ni) {
            int n = n0 + ni * 16 + m16;
            float bias = b2[n];
            #pragma unroll
            for (int rg = 0; rg < 4; ++rg) {
                int row = m0 + mi * 16 + q * 4 + rg;
                if (row < NR) {
                    int t = row >> 5, b = row & 31;
                    float v = clipf(acc[mi][ni][rg] + bias, -100.f, 100.f);
                    out[(size_t)b * T * V + (size_t)(t + 1) * V + n] = v;
                }
            }
        }
}

// ---------------- launch ----------------

extern "C" void kernel_launch(void* const* d_in, const int* in_sizes, int n_in,
                              void* d_out, int out_size, void* d_ws, size_t ws_size,
                              hipStream_t stream) {
    const int*   tgt  = (const int*)d_in[0];
    const float* enc  = (const float*)d_in[1];
    const float* dec  = (const float*)d_in[2];
    const int*   mask = (const int*)d_in[3];
    const float* embt = (const float*)d_in[4];
    const float* wep  = (const float*)d_in[5];  const float* bep = (const float*)d_in[6];
    const float* wq   = (const float*)d_in[7];  const float* bq  = (const float*)d_in[8];
    const float* wk   = (const float*)d_in[9];  const float* bk  = (const float*)d_in[10];
    const float* wv   = (const float*)d_in[11]; const float* bv  = (const float*)d_in[12];
    const float* wo   = (const float*)d_in[13]; const float* bo  = (const float*)d_in[14];
    const float* wih0 = (const float*)d_in[15]; const float* whh0 = (const float*)d_in[16];
    const float* bih0 = (const float*)d_in[17]; const float* bhh0 = (const float*)d_in[18];
    const float* wih1 = (const float*)d_in[19]; const float* whh1 = (const float*)d_in[20];
    const float* bih1 = (const float*)d_in[21]; const float* bhh1 = (const float*)d_in[22];
    const float* wo1  = (const float*)d_in[23]; const float* bo1 = (const float*)d_in[24];
    const float* wo2  = (const float*)d_in[25]; const float* bo2 = (const float*)d_in[26];
    float* out = (float*)d_out;
    char* ws = (char*)d_ws;

    float* kht           = (float*)(ws + 0);
    float* vh            = (float*)(ws + 16777216);
    float* gie           = (float*)(ws + 33554432);
    unsigned short* comb = (unsigned short*)(ws + 45940736);
    unsigned short* h1b  = (unsigned short*)(ws + 50069504);
    unsigned short* w1b  = (unsigned short*)(ws + 52133888);
    unsigned short* w2b  = (unsigned short*)(ws + 53182464);
    float* ctxA          = (float*)(ws + 85950464);
    float* ctxo          = (float*)(ws + 86016000);
    float* h0c           = (float*)(ws + 86081536);
    float* h0n           = (float*)(ws + 86147072);
    float* h1c           = (float*)(ws + 86212608);
    float* h1r           = (float*)(ws + 86278144);
    unsigned* bar        = (unsigned*)(ws + 86343680);   // 32 KB

    hipMemsetAsync(bar, 0, 256 * 32 * sizeof(unsigned), stream);
    hipLaunchKernelGGL(k_zero_t0, dim3(1000), dim3(256), 0, stream, out);
    hipLaunchKernelGGL(k_init_h, dim3(64), dim3(256), 0, stream, dec, h0c, h1c, h1r);
    hipLaunchKernelGGL(k_kv, dim3(B * S), dim3(256), 0, stream, enc, wk, bk, wv, bv, kht, vh);
    hipLaunchKernelGGL(k_gie, dim3(NR), dim3(256), 0, stream, tgt, embt, wep, bep, wih0, bih0, gie);
    hipLaunchKernelGGL(k_cvt, dim3(4096), dim3(256), 0, stream, wo1, wo2, w1b, w2b);
    hipLaunchKernelGGL(k_rec, dim3(GRID_REC), dim3(256), 0, stream,
                       kht, vh, gie, mask, wq, bq, wo, bo,
                       wih0, whh0, bhh0, wih1, bih1, whh1, bhh1,
                       ctxA, ctxo, h0c, h0n, h1c, h1r, comb, bar);
    hipLaunchKernelGGL(k_g1, dim3(4, 16), dim3(256), 0, stream, comb, w1b, bo1, h1b);
    hipLaunchKernelGGL(k_g2, dim3(250, 16), dim3(256), 0, stream, h1b, w2b, bo2, out);
}